// Round 6
// baseline (300.281 us; speedup 1.0000x reference)
//
#include <hip/hip_runtime.h>
#include <hip/hip_bf16.h>

// CGCNN: B=16, N=1024, M=12, F=64, BF=128, 3 conv layers.
// R6: bond pre-swizzled to bf16 MFMA A-fragment order (prep_bond, one pass).
// conv_fused: A = 12 coalesced dwordx4/wave-tile, B via LDS (VGPRs freed),
// manual 2-tile pipeline per wave (all loads for both tiles in flight early).
// Interleave: g = mcol*4 + ct  <->  f = ct*16 + mcol

#define BB 16
#define NN 1024
#define MM 12
#define FF 64
#define S_BN 0.99950037f      // 1/sqrt(1+1e-3)
#define CSTR 68               // csh row stride (ushorts)
#define NT16 12288            // 196608 bond rows / 16

typedef __attribute__((ext_vector_type(8))) short bf16x8;
typedef __attribute__((ext_vector_type(4))) float f32x4;

static __device__ __forceinline__ unsigned short f2bf(float f) {
    union { float f; unsigned u; } c; c.f = f;
    unsigned r = c.u + 0x7fff + ((c.u >> 16) & 1);   // RNE
    return (unsigned short)(r >> 16);
}
static __device__ __forceinline__ float bf2f(unsigned short s) {
    union { unsigned u; float f; } c; c.u = ((unsigned)s) << 16;
    return c.f;
}
__host__ __device__ __forceinline__ int fofg(int g) { return (g & 3) * 16 + (g >> 2); }

// ---- bond -> bf16, MFMA A-fragment order -----------------------------------
// bondf[(((t16*4+kc)*64+lane)*8 + j] = bf16(bond[t16*16 + (lane&15)][kc*32 + (lane>>4)*8 + j])
__global__ __launch_bounds__(256) void prep_bond(const float* __restrict__ bond,
                                                 unsigned short* __restrict__ bondf) {
    int i = blockIdx.x * 256 + threadIdx.x;           // < 12288*4*64 = 3,145,728
    int lane = i & 63;
    int t = i >> 6;
    int kc = t & 3;
    int t16 = t >> 2;
    const float* src = bond + (size_t)(t16 * 16 + (lane & 15)) * 128
                     + kc * 32 + (lane >> 4) * 8;
    float4 v0 = *(const float4*)src;
    float4 v1 = *(const float4*)(src + 4);
    uint4 o;
    o.x = (unsigned)f2bf(v0.x) | ((unsigned)f2bf(v0.y) << 16);
    o.y = (unsigned)f2bf(v0.z) | ((unsigned)f2bf(v0.w) << 16);
    o.z = (unsigned)f2bf(v1.x) | ((unsigned)f2bf(v1.y) << 16);
    o.w = (unsigned)f2bf(v1.z) | ((unsigned)f2bf(v1.w) << 16);
    *(uint4*)(bondf + (size_t)i * 8) = o;
}

// ---- fold BN-a into core weight rows 0..127, double-permuted ---------------
__global__ void fold_w(const float* __restrict__ cw, const float* __restrict__ cb,
                       const float* __restrict__ g_,  const float* __restrict__ bab,
                       float* __restrict__ cwp, float* __restrict__ cbp) {
    int i = blockIdx.x * 256 + threadIdx.x;           // 3*128*64
    if (i >= 3 * 128 * 64) return;
    int g = i & 63;
    int r = (i >> 6) & 127;
    int l = i / (128 * 64);
    int f = fofg(g);
    int k = (r < 64) ? fofg(r) : 64 + fofg(r & 63);
    float gs = g_[l * 64 + f] * S_BN;
    cwp[i] = cw[(l * 256 + k) * 64 + f] * gs;
    if (r == 0)
        cbp[l * 64 + g] = cb[l * 64 + f] * gs + bab[l * 64 + f];
}

// ---- per-layer B panel in MFMA fragment order (5 ct tiles) -----------------
__global__ void prep_wT2(const float* __restrict__ cw, const float* __restrict__ g_,
                         const float* __restrict__ fw, unsigned short* __restrict__ wT2) {
    int i = blockIdx.x * 256 + threadIdx.x;           // 3*4*5*64*8 = 30720
    if (i >= 30720) return;
    int j = i & 7;
    int t = i >> 3;
    int lane = t & 63;  t >>= 6;
    int ct = t % 5;     t /= 5;
    int kc = t & 3;
    int l  = t >> 2;
    int col = ct * 16 + (lane & 15);
    int k   = kc * 32 + (lane >> 4) * 8 + j;
    float v = 0.f;
    if (col < 64)       v = cw[(l * 256 + 128 + k) * 64 + col] * g_[l * 64 + col] * S_BN;
    else if (col == 64) v = fw[l * 256 + 128 + k];
    wT2[i] = f2bf(v);
}

// ---- embedding gather (interleaved x) --------------------------------------
__global__ void embed_k(const int* __restrict__ at, const float* __restrict__ emb,
                        float* __restrict__ x) {
    int i = blockIdx.x * 256 + threadIdx.x;
    int g = i & 63;
    int bn = i >> 6;
    x[i] = emb[at[bn] * FF + fofg(g)];
}

// ---- per-atom projections (interleaved in/out; permuted weights) -----------
__global__ __launch_bounds__(256) void atomproj(
    const float* __restrict__ x, const float* __restrict__ cwp_l,
    const float* __restrict__ cbp_l, const float* __restrict__ fw_l,
    const float* __restrict__ fb_l,
    float* __restrict__ ys, float* __restrict__ yn,
    float* __restrict__ fs, float* __restrict__ fn) {
    __shared__ float wsh[128 * 64];
    __shared__ float xs[4][64];
    int tid = threadIdx.x, w = tid >> 6, lane = tid & 63;
    #pragma unroll
    for (int i = 0; i < 8; i++)
        ((float4*)wsh)[tid + 256 * i] = ((const float4*)cwp_l)[tid + 256 * i];
    int kl = fofg(lane);
    float fw1 = fw_l[kl], fw2 = fw_l[64 + kl];
    float cbv = cbp_l[lane], fbv = fb_l[0];
    __syncthreads();
    #pragma unroll 1
    for (int it = 0; it < 4; it++) {
        int row = (blockIdx.x * 4 + it) * 4 + w;
        float xl = x[(size_t)row * 64 + lane];
        xs[w][lane] = xl;
        float a1 = cbv, a2 = 0.f;
        #pragma unroll 16
        for (int k = 0; k < 64; k++) {
            float xv = xs[w][k];
            a1 += xv * wsh[k * 64 + lane];
            a2 += xv * wsh[(64 + k) * 64 + lane];
        }
        ys[(size_t)row * 64 + lane] = a1;
        yn[(size_t)row * 64 + lane] = a2;
        float p1 = xl * fw1, p2 = xl * fw2;
        #pragma unroll
        for (int off = 32; off; off >>= 1) {
            p1 += __shfl_xor(p1, off, 64);
            p2 += __shfl_xor(p2, off, 64);
        }
        if (lane == 0) { fs[row] = p1 + fbv; fn[row] = p2; }
    }
}

// ---- fused conv layer, 2-tile pipelined ------------------------------------
// wave-tile = 4 atoms = 48 rows = 3 rowtiles; wave does 2 tiles (gw, gw+2048)
__global__ __launch_bounds__(256) void conv_fused(
    const unsigned short* __restrict__ bondf, const unsigned short* __restrict__ wTl,
    const int* __restrict__ nbr, const float* __restrict__ x,
    const float* __restrict__ ys, const float* __restrict__ yn,
    const float* __restrict__ fs, const float* __restrict__ fn,
    const float* __restrict__ bbg, const float* __restrict__ bbb,
    float* __restrict__ xout) {
    __shared__ unsigned short bsh[4 * 5 * 64 * 8];   // 20480 B B-panel
    __shared__ unsigned short csh[4][48 * CSTR];     // 26112 B core dump
    __shared__ float fltw[4][48];
    int tid = threadIdx.x, w = tid >> 6, lane = tid & 63;
    int mcol = lane & 15, q = lane >> 4;

    #pragma unroll
    for (int i = 0; i < 5; i++)
        ((float4*)bsh)[tid + 256 * i] = ((const float4*)wTl)[tid + 256 * i];
    __syncthreads();

    int gw = blockIdx.x * 4 + w;                     // [0,2048)
    int wt0 = gw, wt1 = gw + 2048;
    int a0 = wt0 * 4 + q, a1 = wt1 * 4 + q;
    int b0 = (a0 >> 10) << 10, b1 = (a1 >> 10) << 10;

    // ---- all index loads + A loads for BOTH tiles, in flight early ----
    int jv0[MM], jv1[MM];
    #pragma unroll
    for (int m = 0; m < MM; m++) jv0[m] = nbr[(size_t)a0 * MM + m];
    #pragma unroll
    for (int m = 0; m < MM; m++) jv1[m] = nbr[(size_t)a1 * MM + m];

    bf16x8 A0[3][4], A1[3][4];
    #pragma unroll
    for (int rt = 0; rt < 3; rt++)
        #pragma unroll
        for (int kc = 0; kc < 4; kc++)
            A0[rt][kc] = *(const bf16x8*)(bondf +
                (((size_t)(wt0 * 3 + rt) * 4 + kc) * 64 + lane) * 8);
    #pragma unroll
    for (int rt = 0; rt < 3; rt++)
        #pragma unroll
        for (int kc = 0; kc < 4; kc++)
            A1[rt][kc] = *(const bf16x8*)(bondf +
                (((size_t)(wt1 * 3 + rt) * 4 + kc) * 64 + lane) * 8);

    // gathers for tile0 (dependent on jv0) — issue before MFMA phase
    float fnv0[MM];
    #pragma unroll
    for (int m = 0; m < MM; m++) fnv0[m] = fn[b0 + jv0[m]];
    float fsv0 = fs[a0];
    float4 ysv0 = *(const float4*)(ys + (size_t)a0 * 64 + mcol * 4);
    float4 xv0  = *(const float4*)(x  + (size_t)a0 * 64 + mcol * 4);

    // ---- MFMA tile0 ----
    #pragma unroll
    for (int rt = 0; rt < 3; rt++) {
        f32x4 acc[5];
        #pragma unroll
        for (int ct = 0; ct < 5; ct++) acc[ct] = (f32x4){0.f, 0.f, 0.f, 0.f};
        #pragma unroll
        for (int kc = 0; kc < 4; kc++)
            #pragma unroll
            for (int ct = 0; ct < 5; ct++)
                acc[ct] = __builtin_amdgcn_mfma_f32_16x16x32_bf16(
                    A0[rt][kc], *(const bf16x8*)&bsh[((kc * 5 + ct) * 64 + lane) * 8],
                    acc[ct], 0, 0, 0);
        #pragma unroll
        for (int r = 0; r < 4; r++) {
            int row = rt * 16 + q * 4 + r;
            ushort4 h;
            h.x = f2bf(acc[0][r]); h.y = f2bf(acc[1][r]);
            h.z = f2bf(acc[2][r]); h.w = f2bf(acc[3][r]);
            *(ushort4*)&csh[w][row * CSTR + mcol * 4] = h;
            if (mcol == 0) fltw[w][row] = acc[4][r];
        }
    }

    // gathers for tile1 — issue before tile0 epilogue math
    float fnv1[MM];
    #pragma unroll
    for (int m = 0; m < MM; m++) fnv1[m] = fn[b1 + jv1[m]];
    float fsv1 = fs[a1];
    float4 ysv1 = *(const float4*)(ys + (size_t)a1 * 64 + mcol * 4);
    float4 xv1  = *(const float4*)(x  + (size_t)a1 * 64 + mcol * 4);

    // ---- epilogue tile0 ----
    {
        float lg[MM];
        #pragma unroll
        for (int m = 0; m < MM; m++) lg[m] = fltw[w][q * MM + m] + fsv0 + fnv0[m];
        float mx = -1e30f;
        #pragma unroll
        for (int m = 0; m < MM; m++) mx = fmaxf(mx, lg[m]);
        float sme = 0.f;
        #pragma unroll
        for (int m = 0; m < MM; m++) { lg[m] = __expf(lg[m] - mx); sme += lg[m]; }
        float inv = 1.f / (12.f * sme);
        float s0 = 0.f, s1 = 0.f, s2 = 0.f, s3 = 0.f;
        #pragma unroll
        for (int m = 0; m < MM; m++) {
            ushort4 ch = *(const ushort4*)&csh[w][(q * MM + m) * CSTR + mcol * 4];
            float4 yv = *(const float4*)(yn + (size_t)(b0 + jv0[m]) * 64 + mcol * 4);
            s0 += lg[m] * fmaxf(bf2f(ch.x) + ysv0.x + yv.x, 0.f);
            s1 += lg[m] * fmaxf(bf2f(ch.y) + ysv0.y + yv.y, 0.f);
            s2 += lg[m] * fmaxf(bf2f(ch.z) + ysv0.z + yv.z, 0.f);
            s3 += lg[m] * fmaxf(bf2f(ch.w) + ysv0.w + yv.w, 0.f);
        }
        float4 o;
        o.x = fmaxf(xv0.x + bbg[mcol]      * (s0 * inv * S_BN) + bbb[mcol],      0.f);
        o.y = fmaxf(xv0.y + bbg[16 + mcol] * (s1 * inv * S_BN) + bbb[16 + mcol], 0.f);
        o.z = fmaxf(xv0.z + bbg[32 + mcol] * (s2 * inv * S_BN) + bbb[32 + mcol], 0.f);
        o.w = fmaxf(xv0.w + bbg[48 + mcol] * (s3 * inv * S_BN) + bbb[48 + mcol], 0.f);
        *(float4*)(xout + (size_t)a0 * 64 + mcol * 4) = o;
    }

    // ---- MFMA tile1 (csh reuse is same-wave program-ordered) ----
    #pragma unroll
    for (int rt = 0; rt < 3; rt++) {
        f32x4 acc[5];
        #pragma unroll
        for (int ct = 0; ct < 5; ct++) acc[ct] = (f32x4){0.f, 0.f, 0.f, 0.f};
        #pragma unroll
        for (int kc = 0; kc < 4; kc++)
            #pragma unroll
            for (int ct = 0; ct < 5; ct++)
                acc[ct] = __builtin_amdgcn_mfma_f32_16x16x32_bf16(
                    A1[rt][kc], *(const bf16x8*)&bsh[((kc * 5 + ct) * 64 + lane) * 8],
                    acc[ct], 0, 0, 0);
        #pragma unroll
        for (int r = 0; r < 4; r++) {
            int row = rt * 16 + q * 4 + r;
            ushort4 h;
            h.x = f2bf(acc[0][r]); h.y = f2bf(acc[1][r]);
            h.z = f2bf(acc[2][r]); h.w = f2bf(acc[3][r]);
            *(ushort4*)&csh[w][row * CSTR + mcol * 4] = h;
            if (mcol == 0) fltw[w][row] = acc[4][r];
        }
    }

    // ---- epilogue tile1 ----
    {
        float lg[MM];
        #pragma unroll
        for (int m = 0; m < MM; m++) lg[m] = fltw[w][q * MM + m] + fsv1 + fnv1[m];
        float mx = -1e30f;
        #pragma unroll
        for (int m = 0; m < MM; m++) mx = fmaxf(mx, lg[m]);
        float sme = 0.f;
        #pragma unroll
        for (int m = 0; m < MM; m++) { lg[m] = __expf(lg[m] - mx); sme += lg[m]; }
        float inv = 1.f / (12.f * sme);
        float s0 = 0.f, s1 = 0.f, s2 = 0.f, s3 = 0.f;
        #pragma unroll
        for (int m = 0; m < MM; m++) {
            ushort4 ch = *(const ushort4*)&csh[w][(q * MM + m) * CSTR + mcol * 4];
            float4 yv = *(const float4*)(yn + (size_t)(b1 + jv1[m]) * 64 + mcol * 4);
            s0 += lg[m] * fmaxf(bf2f(ch.x) + ysv1.x + yv.x, 0.f);
            s1 += lg[m] * fmaxf(bf2f(ch.y) + ysv1.y + yv.y, 0.f);
            s2 += lg[m] * fmaxf(bf2f(ch.z) + ysv1.z + yv.z, 0.f);
            s3 += lg[m] * fmaxf(bf2f(ch.w) + ysv1.w + yv.w, 0.f);
        }
        float4 o;
        o.x = fmaxf(xv1.x + bbg[mcol]      * (s0 * inv * S_BN) + bbb[mcol],      0.f);
        o.y = fmaxf(xv1.y + bbg[16 + mcol] * (s1 * inv * S_BN) + bbb[16 + mcol], 0.f);
        o.z = fmaxf(xv1.z + bbg[32 + mcol] * (s2 * inv * S_BN) + bbb[32 + mcol], 0.f);
        o.w = fmaxf(xv1.w + bbg[48 + mcol] * (s3 * inv * S_BN) + bbb[48 + mcol], 0.f);
        *(float4*)(xout + (size_t)a1 * 64 + mcol * 4) = o;
    }
}

// ---- pooling gather + dense + relu (x interleaved -> out standard) ---------
__global__ __launch_bounds__(256) void final_k(
    const float* __restrict__ x, const int* __restrict__ tidx,
    const float* __restrict__ dw, const float* __restrict__ db,
    float* __restrict__ out) {
    __shared__ float xs[4][64];
    __shared__ float wsh[64 * 64];
    int tid = threadIdx.x;
    int w = tid >> 6, lane = tid & 63;
    const float4* src = (const float4*)dw;
    float4* dst = (float4*)wsh;
    #pragma unroll
    for (int i = 0; i < 4; i++) dst[tid + 256 * i] = src[tid + 256 * i];
    int row = blockIdx.x * 4 + w;
    int b = row >> 6;
    int t = tidx[row];
    float xv = x[((size_t)b * NN + t) * 64 + lane];   // feature fofg(lane)
    xs[w][lane] = fmaxf(xv, 0.f);
    __syncthreads();
    float a = db[lane];
    #pragma unroll
    for (int g = 0; g < 64; g++)
        a += xs[w][g] * wsh[fofg(g) * 64 + lane];
    out[row * 64 + lane] = fmaxf(a, 0.f);
}

extern "C" void kernel_launch(void* const* d_in, const int* in_sizes, int n_in,
                              void* d_out, int out_size, void* d_ws, size_t ws_size,
                              hipStream_t stream) {
    const int*   at   = (const int*)d_in[0];
    const float* bond = (const float*)d_in[1];
    const int*   nbr  = (const int*)d_in[2];
    const int*   tgt  = (const int*)d_in[3];
    const float* emb  = (const float*)d_in[4];
    const float* cw   = (const float*)d_in[5];
    const float* cb   = (const float*)d_in[6];
    const float* fw   = (const float*)d_in[7];
    const float* fb   = (const float*)d_in[8];
    const float* bag  = (const float*)d_in[9];
    const float* bab  = (const float*)d_in[10];
    const float* bbg  = (const float*)d_in[11];
    const float* bbb  = (const float*)d_in[12];
    const float* dw   = (const float*)d_in[13];
    const float* db   = (const float*)d_in[14];

    float* ws  = (float*)d_ws;
    float* xA  = ws;
    float* xB  = xA + (size_t)BB * NN * FF;
    float* cwp = xB + (size_t)BB * NN * FF;
    float* cbp = cwp + 3 * 128 * 64;
    float* ys  = cbp + 192;
    float* yn  = ys + (size_t)BB * NN * FF;
    float* fs  = yn + (size_t)BB * NN * FF;
    float* fn  = fs + (size_t)BB * NN;
    unsigned short* wT2   = (unsigned short*)(fn + (size_t)BB * NN);  // 30720 bf16
    unsigned short* bondf = wT2 + 30720;              // 25,165,824 bf16 (~50 MB)
    // total ~67 MB

    prep_bond<<<NT16, 256, 0, stream>>>(bond, bondf);
    fold_w<<<96, 256, 0, stream>>>(cw, cb, bag, bab, cwp, cbp);
    prep_wT2<<<120, 256, 0, stream>>>(cw, bag, fw, wT2);
    embed_k<<<(BB * NN * FF) / 256, 256, 0, stream>>>(at, emb, xA);

    float* xin = xA;
    float* xout = xB;
    for (int l = 0; l < 3; l++) {
        atomproj<<<BB * NN / 16, 256, 0, stream>>>(
            xin, cwp + (size_t)l * 128 * 64, cbp + l * 64, fw + l * 256, fb + l,
            ys, yn, fs, fn);
        conv_fused<<<512, 256, 0, stream>>>(
            bondf, wT2 + (size_t)l * 10240, nbr, xin,
            ys, yn, fs, fn, bbg + l * 64, bbb + l * 64, xout);
        float* t = xin; xin = xout; xout = t;
    }

    final_k<<<BB * 64 / 4, 256, 0, stream>>>(xin, tgt, dw, db, (float*)d_out);
}